// Round 1
// baseline (649.495 us; speedup 1.0000x reference)
//
#include <hip/hip_runtime.h>

typedef __bf16 bf16x8 __attribute__((ext_vector_type(8)));
typedef __bf16 bf16x4 __attribute__((ext_vector_type(4)));
typedef float  f32x4  __attribute__((ext_vector_type(4)));

static constexpr int Bb = 4, T = 8192, H = 1024, R = 1024;
static constexpr int BT = Bb * T;   // 32768 rows
static constexpr int N1 = 2 * R;    // 2048 (z|h columns)
static constexpr int CH = 64;       // scan chunks
static constexpr int L  = T / CH;   // 128 steps/chunk

// ---- async global -> LDS (16B per lane, wave-uniform LDS base) ----
__device__ __forceinline__ void g2lds16(const void* g, void* l) {
  __builtin_amdgcn_global_load_lds(
      (const __attribute__((address_space(1))) unsigned int*)g,
      (__attribute__((address_space(3))) unsigned int*)l, 16, 0, 0);
}

// ---- simple f32 -> bf16 cast (weights) ----
__global__ __launch_bounds__(256) void cast_f32_bf16(const float* __restrict__ in,
                                                     __bf16* __restrict__ out, int n4) {
  int i = blockIdx.x * 256 + threadIdx.x;
  if (i >= n4) return;
  const f32x4 v = *(const f32x4*)(in + (size_t)i * 4);
  bf16x4 o;
  o[0] = (__bf16)v[0]; o[1] = (__bf16)v[1]; o[2] = (__bf16)v[2]; o[3] = (__bf16)v[3];
  *(bf16x4*)(out + (size_t)i * 4) = o;
}

// ---- residual causal depthwise conv + cast to bf16 ----
__global__ __launch_bounds__(256) void conv_residual_cast(const float* __restrict__ x,
                                                          const float* __restrict__ cw,
                                                          const float* __restrict__ cb,
                                                          __bf16* __restrict__ xc) {
  const size_t i4 = (size_t)blockIdx.x * 256 + threadIdx.x;
  const size_t v  = i4 * 4;                    // element index into [B,T,H]
  const int    h  = (int)(v & (size_t)(H - 1));
  const size_t bt = v >> 10;                   // /H
  const int    t  = (int)(bt & (size_t)(T - 1));
  f32x4 acc = *(const f32x4*)(cb + h);
  const f32x4 xv = *(const f32x4*)(x + v);
#pragma unroll
  for (int i = 0; i < 4; ++i) {
    const int tt = t - 3 + i;
    if (tt >= 0) {
      const f32x4 xi = *(const f32x4*)(x + (bt - 3 + i) * H + h);
      const f32x4 wi = *(const f32x4*)(cw + i * H + h);
      acc += wi * xi;
    }
  }
  acc += xv;  // residual
  bf16x4 o;
  o[0] = (__bf16)acc[0]; o[1] = (__bf16)acc[1]; o[2] = (__bf16)acc[2]; o[3] = (__bf16)acc[3];
  *(bf16x4*)(xc + v) = o;
}

// ---- C[M,N] = A[M,K] @ B[N,K]^T, bf16 in, fp32 acc, OUT_T out ----
// 128x128 tile, BK=32, 256 threads = 4 waves, each wave 64x64 via 4x4 MFMA 16x16x32.
template <typename OUT_T>
__global__ __launch_bounds__(256) void gemm_bt(const __bf16* __restrict__ A,
                                               const __bf16* __restrict__ Bm,
                                               OUT_T* __restrict__ C,
                                               int M, int N, int K) {
  __shared__ __align__(16) __bf16 sA[128 * 32];
  __shared__ __align__(16) __bf16 sB[128 * 32];
  const int tid  = threadIdx.x;
  const int wave = tid >> 6;
  const int lane = tid & 63;
  const int lr = lane & 15;   // fragment row/col within 16
  const int lq = lane >> 4;   // quad 0..3
  const int bm0 = blockIdx.y * 128;
  const int bn0 = blockIdx.x * 128;
  const int wm = (wave >> 1) * 64;
  const int wn = (wave & 1) * 64;

  f32x4 acc[4][4] = {};

  // staging: chunk index li = c*256 + tid; row = li>>2; kq = (li&3)*8 elems
  const size_t aBase = (size_t)(bm0 + (tid >> 2)) * K + (tid & 3) * 8;
  const size_t bBase = (size_t)(bn0 + (tid >> 2)) * K + (tid & 3) * 8;
  const int ldsOff = (tid & ~63) * 8;  // elements; wave-uniform

  for (int k0 = 0; k0 < K; k0 += 32) {
    g2lds16(A  + aBase + k0,                 sA + ldsOff);
    g2lds16(A  + aBase + (size_t)64 * K + k0, sA + ldsOff + 2048);
    g2lds16(Bm + bBase + k0,                 sB + ldsOff);
    g2lds16(Bm + bBase + (size_t)64 * K + k0, sB + ldsOff + 2048);
    __syncthreads();
    bf16x8 af[4], bfr[4];
#pragma unroll
    for (int i = 0; i < 4; ++i) {
      af[i]  = *(const bf16x8*)(sA + (wm + i * 16 + lr) * 32 + lq * 8);
      bfr[i] = *(const bf16x8*)(sB + (wn + i * 16 + lr) * 32 + lq * 8);
    }
#pragma unroll
    for (int i = 0; i < 4; ++i)
#pragma unroll
      for (int j = 0; j < 4; ++j)
        acc[i][j] = __builtin_amdgcn_mfma_f32_16x16x32_bf16(af[i], bfr[j], acc[i][j], 0, 0, 0);
    __syncthreads();
  }
  // epilogue: C/D layout col = lane&15, row = (lane>>4)*4 + reg
#pragma unroll
  for (int i = 0; i < 4; ++i)
#pragma unroll
    for (int j = 0; j < 4; ++j) {
      const int col = bn0 + wn + j * 16 + lr;
#pragma unroll
      for (int rr = 0; rr < 4; ++rr) {
        const int row = bm0 + wm + i * 16 + lq * 4 + rr;
        C[(size_t)row * N + col] = (OUT_T)acc[i][j][rr];
      }
    }
}

// ---- scan pass 1: per-(b, chunk, r) aggregate (A,B): h_end = A*h_start + B ----
__global__ __launch_bounds__(256) void scan_pass1(const __bf16* __restrict__ zh,
                                                  float* __restrict__ aggA,
                                                  float* __restrict__ aggB) {
  const int r = blockIdx.x * 256 + threadIdx.x;
  const int c = blockIdx.y;
  const int b = blockIdx.z;
  size_t base = ((size_t)b * T + (size_t)c * L) * N1 + r;
  float Aacc = 1.f, Bacc = 0.f;
#pragma unroll 4
  for (int t = 0; t < L; ++t) {
    const float s  = (float)zh[base];
    const float hh = (float)zh[base + R];
    base += N1;
    const float z = 1.f / (1.f + __expf(-s));
    const float a = 1.f - z;
    Bacc = a * Bacc + z * hh;
    Aacc *= a;
  }
  const size_t o = ((size_t)b * CH + c) * R + r;
  aggA[o] = Aacc;
  aggB[o] = Bacc;
}

// ---- scan pass 2: scan the 64 chunk aggregates per (b,r); write carry-in per chunk ----
__global__ __launch_bounds__(256) void scan_pass2(const float* __restrict__ aggA,
                                                  const float* __restrict__ aggB,
                                                  float* __restrict__ carry) {
  const int idx = blockIdx.x * 256 + threadIdx.x;  // b*R + r
  const int b = idx >> 10;
  const int r = idx & (R - 1);
  float h = 0.f;
#pragma unroll 8
  for (int c = 0; c < CH; ++c) {
    const size_t o = ((size_t)b * CH + c) * R + r;
    carry[o] = h;
    h = aggA[o] * h + aggB[o];
  }
}

// ---- scan pass 3: apply carry, recompute gates, emit h_o (bf16) ----
__global__ __launch_bounds__(256) void scan_pass3(const __bf16* __restrict__ zh,
                                                  const float* __restrict__ carry,
                                                  __bf16* __restrict__ ho) {
  const int r = blockIdx.x * 256 + threadIdx.x;
  const int c = blockIdx.y;
  const int b = blockIdx.z;
  size_t base  = ((size_t)b * T + (size_t)c * L) * N1 + r;
  size_t obase = ((size_t)b * T + (size_t)c * L) * R + r;
  float h = carry[((size_t)b * CH + c) * R + r];
#pragma unroll 4
  for (int t = 0; t < L; ++t) {
    const float s  = (float)zh[base];
    const float hh = (float)zh[base + R];
    base += N1;
    const float z = 1.f / (1.f + __expf(-s));
    h = (1.f - z) * h + z * hh;
    ho[obase] = (__bf16)h;
    obase += R;
  }
}

extern "C" void kernel_launch(void* const* d_in, const int* in_sizes, int n_in,
                              void* d_out, int out_size, void* d_ws, size_t ws_size,
                              hipStream_t stream) {
  const float* x      = (const float*)d_in[0];
  const float* w_zh   = (const float*)d_in[1];
  const float* w_out  = (const float*)d_in[2];
  const float* conv_w = (const float*)d_in[3];
  const float* conv_b = (const float*)d_in[4];
  float* out = (float*)d_out;

  char* ws = (char*)d_ws;
  size_t off = 0;
  __bf16* wzh_b  = (__bf16*)(ws + off); off += (size_t)N1 * H * 2;        // 4 MiB
  __bf16* wout_b = (__bf16*)(ws + off); off += (size_t)H * R * 2;         // 2 MiB
  __bf16* xc     = (__bf16*)(ws + off); off += (size_t)BT * H * 2;        // 64 MiB
  __bf16* zh     = (__bf16*)(ws + off); off += (size_t)BT * N1 * 2;       // 128 MiB
  float*  aggA   = (float*)(ws + off);  off += (size_t)Bb * CH * R * 4;   // 1 MiB
  float*  aggB   = (float*)(ws + off);  off += (size_t)Bb * CH * R * 4;   // 1 MiB
  float*  carry  = (float*)(ws + off);  off += (size_t)Bb * CH * R * 4;   // 1 MiB
  __bf16* ho = xc;  // alias: xc is dead after GEMM1

  cast_f32_bf16<<<(N1 * H / 4 + 255) / 256, 256, 0, stream>>>(w_zh, wzh_b, N1 * H / 4);
  cast_f32_bf16<<<(H * R / 4 + 255) / 256, 256, 0, stream>>>(w_out, wout_b, H * R / 4);
  conv_residual_cast<<<BT * H / 4 / 256, 256, 0, stream>>>(x, conv_w, conv_b, xc);
  gemm_bt<__bf16><<<dim3(N1 / 128, BT / 128), 256, 0, stream>>>(xc, wzh_b, zh, BT, N1, H);
  scan_pass1<<<dim3(R / 256, CH, Bb), 256, 0, stream>>>(zh, aggA, aggB);
  scan_pass2<<<Bb * R / 256, 256, 0, stream>>>(aggA, aggB, carry);
  scan_pass3<<<dim3(R / 256, CH, Bb), 256, 0, stream>>>(zh, carry, ho);
  gemm_bt<float><<<dim3(H / 128, BT / 128), 256, 0, stream>>>(ho, wout_b, out, BT, H, R);
}

// Round 2
// 609.295 us; speedup vs baseline: 1.0660x; 1.0660x over previous
//
#include <hip/hip_runtime.h>

typedef __bf16 bf16x8 __attribute__((ext_vector_type(8)));
typedef __bf16 bf16x4 __attribute__((ext_vector_type(4)));
typedef float  f32x4  __attribute__((ext_vector_type(4)));
typedef float  f32x16 __attribute__((ext_vector_type(16)));

static constexpr int Bb = 4, T = 8192, H = 1024, R = 1024;
static constexpr int BT = Bb * T;   // 32768 rows
static constexpr int N1 = 2 * R;    // 2048 (z|h columns)
static constexpr int CH = 64;       // scan chunks
static constexpr int L  = T / CH;   // 128 steps/chunk

// ---- async global -> LDS (16B per lane, wave-uniform LDS base) ----
__device__ __forceinline__ void g2lds16(const void* g, void* l) {
  __builtin_amdgcn_global_load_lds(
      (const __attribute__((address_space(1))) unsigned int*)g,
      (__attribute__((address_space(3))) unsigned int*)l, 16, 0, 0);
}

// ---- simple f32 -> bf16 cast (weights) ----
__global__ __launch_bounds__(256) void cast_f32_bf16(const float* __restrict__ in,
                                                     __bf16* __restrict__ out, int n4) {
  int i = blockIdx.x * 256 + threadIdx.x;
  if (i >= n4) return;
  const f32x4 v = *(const f32x4*)(in + (size_t)i * 4);
  bf16x4 o;
  o[0] = (__bf16)v[0]; o[1] = (__bf16)v[1]; o[2] = (__bf16)v[2]; o[3] = (__bf16)v[3];
  *(bf16x4*)(out + (size_t)i * 4) = o;
}

// ---- residual causal depthwise conv + cast to bf16 ----
__global__ __launch_bounds__(256) void conv_residual_cast(const float* __restrict__ x,
                                                          const float* __restrict__ cw,
                                                          const float* __restrict__ cb,
                                                          __bf16* __restrict__ xc) {
  const size_t i4 = (size_t)blockIdx.x * 256 + threadIdx.x;
  const size_t v  = i4 * 4;                    // element index into [B,T,H]
  const int    h  = (int)(v & (size_t)(H - 1));
  const size_t bt = v >> 10;                   // /H
  const int    t  = (int)(bt & (size_t)(T - 1));
  f32x4 acc = *(const f32x4*)(cb + h);
  const f32x4 xv = *(const f32x4*)(x + v);
#pragma unroll
  for (int i = 0; i < 4; ++i) {
    const int tt = t - 3 + i;
    if (tt >= 0) {
      const f32x4 xi = *(const f32x4*)(x + (bt - 3 + i) * H + h);
      const f32x4 wi = *(const f32x4*)(cw + i * H + h);
      acc += wi * xi;
    }
  }
  acc += xv;  // residual
  bf16x4 o;
  o[0] = (__bf16)acc[0]; o[1] = (__bf16)acc[1]; o[2] = (__bf16)acc[2]; o[3] = (__bf16)acc[3];
  *(bf16x4*)(xc + v) = o;
}

// ---- C[M,N] = A[M,K] @ B[N,K]^T, bf16 in, fp32 acc, OUT_T out ----
// 128x128 tile, BK=64, 256 threads = 4 waves, each wave 64x64 via 2x2 MFMA 32x32x16.
// LDS layout: sX[row][64] with XOR swizzle on 8-elem chunks: logical chunk c of
// row r is stored at chunk position c ^ (r&7). Swizzle is applied on the GLOBAL
// source address during global_load_lds staging (LDS dest is wave-contiguous).
template <typename OUT_T>
__global__ __launch_bounds__(256) void gemm_bt(const __bf16* __restrict__ A,
                                               const __bf16* __restrict__ Bm,
                                               OUT_T* __restrict__ C,
                                               int M, int N, int K) {
  __shared__ __align__(16) __bf16 sA[128 * 64];
  __shared__ __align__(16) __bf16 sB[128 * 64];
  const int tid  = threadIdx.x;
  const int wave = tid >> 6;
  const int lane = tid & 63;
  const int ln = lane & 31;   // m/n index within 32
  const int kb = lane >> 5;   // k-block 0/1 within a 16-wide k-step
  const int bm0 = blockIdx.y * 128;
  const int bn0 = blockIdx.x * 128;
  const int wm = (wave >> 1) * 64;
  const int wn = (wave & 1) * 64;

  f32x16 acc[2][2] = {};

  // staging: 4 calls per matrix; li = c*256+tid; row = li>>3; dest chunk = li&7;
  // source chunk = dest ^ (row&7)
  int srow[4], sgc[4], sldsE[4];
#pragma unroll
  for (int c = 0; c < 4; ++c) {
    const int li = c * 256 + tid;
    srow[c] = li >> 3;
    sgc[c]  = (li & 7) ^ (srow[c] & 7);
    sldsE[c] = (c * 256 + (tid & ~63)) * 8;  // wave-uniform elem offset
  }

  for (int k0 = 0; k0 < K; k0 += 64) {
#pragma unroll
    for (int c = 0; c < 4; ++c) {
      g2lds16(A  + (size_t)(bm0 + srow[c]) * K + k0 + sgc[c] * 8, sA + sldsE[c]);
      g2lds16(Bm + (size_t)(bn0 + srow[c]) * K + k0 + sgc[c] * 8, sB + sldsE[c]);
    }
    __syncthreads();
#pragma unroll
    for (int ks = 0; ks < 4; ++ks) {
      bf16x8 af[2], bfr[2];
#pragma unroll
      for (int i = 0; i < 2; ++i) {
        const int ra = wm + i * 32 + ln;
        af[i]  = *(const bf16x8*)(sA + ra * 64 + (((2 * ks + kb) ^ (ra & 7)) * 8));
        const int rb = wn + i * 32 + ln;
        bfr[i] = *(const bf16x8*)(sB + rb * 64 + (((2 * ks + kb) ^ (rb & 7)) * 8));
      }
#pragma unroll
      for (int i = 0; i < 2; ++i)
#pragma unroll
        for (int j = 0; j < 2; ++j)
          acc[i][j] = __builtin_amdgcn_mfma_f32_32x32x16_bf16(af[i], bfr[j], acc[i][j], 0, 0, 0);
    }
    __syncthreads();
  }
  // epilogue: 32x32 C/D layout: col = lane&31, row = (reg&3) + 8*(reg>>2) + 4*(lane>>5)
#pragma unroll
  for (int i = 0; i < 2; ++i)
#pragma unroll
    for (int j = 0; j < 2; ++j) {
      const int col = bn0 + wn + j * 32 + ln;
#pragma unroll
      for (int rr = 0; rr < 16; ++rr) {
        const int row = bm0 + wm + i * 32 + (rr & 3) + 8 * (rr >> 2) + 4 * kb;
        C[(size_t)row * N + col] = (OUT_T)acc[i][j][rr];
      }
    }
}

// ---- scan pass 1: per-(b, chunk, r) aggregate (A,B): h_end = A*h_start + B ----
__global__ __launch_bounds__(256) void scan_pass1(const __bf16* __restrict__ zh,
                                                  float* __restrict__ aggA,
                                                  float* __restrict__ aggB) {
  const int r = blockIdx.x * 256 + threadIdx.x;
  const int c = blockIdx.y;
  const int b = blockIdx.z;
  size_t base = ((size_t)b * T + (size_t)c * L) * N1 + r;
  float Aacc = 1.f, Bacc = 0.f;
#pragma unroll 4
  for (int t = 0; t < L; ++t) {
    const float s  = (float)zh[base];
    const float hh = (float)zh[base + R];
    base += N1;
    const float z = 1.f / (1.f + __expf(-s));
    const float a = 1.f - z;
    Bacc = a * Bacc + z * hh;
    Aacc *= a;
  }
  const size_t o = ((size_t)b * CH + c) * R + r;
  aggA[o] = Aacc;
  aggB[o] = Bacc;
}

// ---- scan pass 2: scan the 64 chunk aggregates per (b,r); write carry-in per chunk ----
__global__ __launch_bounds__(256) void scan_pass2(const float* __restrict__ aggA,
                                                  const float* __restrict__ aggB,
                                                  float* __restrict__ carry) {
  const int idx = blockIdx.x * 256 + threadIdx.x;  // b*R + r
  const int b = idx >> 10;
  const int r = idx & (R - 1);
  float h = 0.f;
#pragma unroll 8
  for (int c = 0; c < CH; ++c) {
    const size_t o = ((size_t)b * CH + c) * R + r;
    carry[o] = h;
    h = aggA[o] * h + aggB[o];
  }
}

// ---- scan pass 3: apply carry, recompute gates, emit h_o (bf16) ----
__global__ __launch_bounds__(256) void scan_pass3(const __bf16* __restrict__ zh,
                                                  const float* __restrict__ carry,
                                                  __bf16* __restrict__ ho) {
  const int r = blockIdx.x * 256 + threadIdx.x;
  const int c = blockIdx.y;
  const int b = blockIdx.z;
  size_t base  = ((size_t)b * T + (size_t)c * L) * N1 + r;
  size_t obase = ((size_t)b * T + (size_t)c * L) * R + r;
  float h = carry[((size_t)b * CH + c) * R + r];
#pragma unroll 4
  for (int t = 0; t < L; ++t) {
    const float s  = (float)zh[base];
    const float hh = (float)zh[base + R];
    base += N1;
    const float z = 1.f / (1.f + __expf(-s));
    h = (1.f - z) * h + z * hh;
    ho[obase] = (__bf16)h;
    obase += R;
  }
}

extern "C" void kernel_launch(void* const* d_in, const int* in_sizes, int n_in,
                              void* d_out, int out_size, void* d_ws, size_t ws_size,
                              hipStream_t stream) {
  const float* x      = (const float*)d_in[0];
  const float* w_zh   = (const float*)d_in[1];
  const float* w_out  = (const float*)d_in[2];
  const float* conv_w = (const float*)d_in[3];
  const float* conv_b = (const float*)d_in[4];
  float* out = (float*)d_out;

  char* ws = (char*)d_ws;
  size_t off = 0;
  __bf16* wzh_b  = (__bf16*)(ws + off); off += (size_t)N1 * H * 2;        // 4 MiB
  __bf16* wout_b = (__bf16*)(ws + off); off += (size_t)H * R * 2;         // 2 MiB
  __bf16* xc     = (__bf16*)(ws + off); off += (size_t)BT * H * 2;        // 64 MiB
  __bf16* zh     = (__bf16*)(ws + off); off += (size_t)BT * N1 * 2;       // 128 MiB
  float*  aggA   = (float*)(ws + off);  off += (size_t)Bb * CH * R * 4;   // 1 MiB
  float*  aggB   = (float*)(ws + off);  off += (size_t)Bb * CH * R * 4;   // 1 MiB
  float*  carry  = (float*)(ws + off);  off += (size_t)Bb * CH * R * 4;   // 1 MiB
  __bf16* ho = xc;  // alias: xc is dead after GEMM1

  cast_f32_bf16<<<(N1 * H / 4 + 255) / 256, 256, 0, stream>>>(w_zh, wzh_b, N1 * H / 4);
  cast_f32_bf16<<<(H * R / 4 + 255) / 256, 256, 0, stream>>>(w_out, wout_b, H * R / 4);
  conv_residual_cast<<<BT * H / 4 / 256, 256, 0, stream>>>(x, conv_w, conv_b, xc);
  gemm_bt<__bf16><<<dim3(N1 / 128, BT / 128), 256, 0, stream>>>(xc, wzh_b, zh, BT, N1, H);
  scan_pass1<<<dim3(R / 256, CH, Bb), 256, 0, stream>>>(zh, aggA, aggB);
  scan_pass2<<<Bb * R / 256, 256, 0, stream>>>(aggA, aggB, carry);
  scan_pass3<<<dim3(R / 256, CH, Bb), 256, 0, stream>>>(zh, carry, ho);
  gemm_bt<float><<<dim3(H / 128, BT / 128), 256, 0, stream>>>(ho, wout_b, out, BT, H, R);
}